// Round 1
// baseline (1101.652 us; speedup 1.0000x reference)
//
#include <hip/hip_runtime.h>

// MaxUnpooling2D (tf.scatter_nd-style sum-scatter):
//   pool: f32 [16,128,128,64]  (64 MiB)
//   ind:  int32 [16,128,128,64] (JAX demotes jnp.int64->int32 without x64) (64 MiB)
//   out:  f32 [16,256,256,64]  (256 MiB), zeroed then out[b*OUT_PER_B + ind] += pool
// Duplicates must sum -> atomicAdd (device-scope by default, XCD-safe).

constexpr long long IN_PER_B  = 128LL * 128 * 64;   // 2^20 elements per batch (input)
constexpr long long OUT_PER_B = 256LL * 256 * 64;   // 2^22 elements per batch (output)
constexpr long long N         = 16 * IN_PER_B;      // 2^24 total input elements
constexpr int LOG2_IN_PER_B   = 20;                 // IN_PER_B is a power of two

__global__ void __launch_bounds__(256) unpool_scatter(
        const float4* __restrict__ pool4,
        const int4*   __restrict__ ind4,
        float*        __restrict__ out) {
    const long long n4     = N >> 2;                         // vec4 count
    const long long stride = (long long)gridDim.x * blockDim.x;
    long long i = (long long)blockIdx.x * blockDim.x + threadIdx.x;
    for (; i < n4; i += stride) {
        // 4 consecutive elements always share a batch (IN_PER_B % 4 == 0)
        const float4 v  = pool4[i];
        const int4   id = ind4[i];
        const long long bofs = ((i << 2) >> LOG2_IN_PER_B) * OUT_PER_B;
        atomicAdd(&out[bofs + (long long)id.x], v.x);
        atomicAdd(&out[bofs + (long long)id.y], v.y);
        atomicAdd(&out[bofs + (long long)id.z], v.z);
        atomicAdd(&out[bofs + (long long)id.w], v.w);
    }
}

extern "C" void kernel_launch(void* const* d_in, const int* in_sizes, int n_in,
                              void* d_out, int out_size, void* d_ws, size_t ws_size,
                              hipStream_t stream) {
    const float* pool = (const float*)d_in[0];
    const int*   ind  = (const int*)d_in[1];
    float*       out  = (float*)d_out;

    // Output is re-poisoned to 0xAA before every timed call — zero it ourselves.
    hipMemsetAsync(out, 0, (size_t)out_size * sizeof(float), stream);

    // 2048 blocks x 256 threads = 8192 waves = full resident-wave capacity;
    // grid-stride, 8 vec4 iterations per thread.
    const int blocks  = 2048;
    const int threads = 256;
    unpool_scatter<<<blocks, threads, 0, stream>>>(
        (const float4*)pool, (const int4*)ind, out);
}